// Round 3
// baseline (261.177 us; speedup 1.0000x reference)
//
#include <hip/hip_runtime.h>
#include <cstdint>

typedef unsigned short ushortT;
typedef __attribute__((ext_vector_type(8))) short short8;      // 8 bf16 = 4 VGPRs (MFMA A/B frag)
typedef __attribute__((ext_vector_type(8))) unsigned short ushort8v;
typedef __attribute__((ext_vector_type(4))) float float4v;

#define ATT_SCALE 0.17677669529663687f   // 32^-0.5

__device__ inline float bf2f(unsigned short u) {
    union { unsigned int i; float f; } x; x.i = ((unsigned int)u) << 16; return x.f;
}
__device__ inline unsigned short f2bf(float f) {
    union { float f; unsigned int i; } x; x.f = f;
    unsigned int i = x.i;
    i += 0x7fffu + ((i >> 16) & 1u);      // RNE
    return (unsigned short)(i >> 16);
}

__device__ inline void gld_lds16(const ushortT* g, ushortT* l) {
    // async global->LDS, 16B/lane; LDS dest = wave-uniform base + lane*16
    __builtin_amdgcn_global_load_lds((const __attribute__((address_space(1))) void*)g,
                                     (__attribute__((address_space(3))) void*)l, 16, 0, 0);
}

// ---------------------------------------------------------------------------
// Dtype probe: bf16 N(0,1) data -> ~100% of ushorts have exp field in [100,140];
// fp32 N(0,1) read as ushorts -> only ~58% (low halves are uniform mantissa bits).
// flag = 1 (bf16) / 0 (fp32).
// ---------------------------------------------------------------------------
__global__ void detect_dtype(const ushortT* __restrict__ x, int* __restrict__ flag) {
    __shared__ int cnt;
    if (threadIdx.x == 0) cnt = 0;
    __syncthreads();
    int c = 0;
    for (int i = threadIdx.x; i < 4096; i += 256) {
        unsigned e = (x[i] >> 7) & 0xFFu;
        if (e >= 100u && e <= 140u) c++;
    }
    atomicAdd(&cnt, c);
    __syncthreads();
    if (threadIdx.x == 0) *flag = (cnt > 3600) ? 1 : 0;
}

// ---------------------------------------------------------------------------
// Convert weights -> bf16 and biases -> fp32 (source dtype per flag).
// ---------------------------------------------------------------------------
__global__ __launch_bounds__(256) void convert_params(const void* __restrict__ w_qkv,
                                                      const void* __restrict__ w_proj,
                                                      const void* __restrict__ b_qkv,
                                                      const void* __restrict__ b_proj,
                                                      ushortT* __restrict__ wqkvB,
                                                      ushortT* __restrict__ wprojB,
                                                      float* __restrict__ bqF,
                                                      float* __restrict__ bpF,
                                                      const int* __restrict__ flagp) {
    const int isBf = *flagp;
    int i = blockIdx.x * 256 + threadIdx.x;
    if (i < 196608) {
        wqkvB[i] = isBf ? ((const ushortT*)w_qkv)[i] : f2bf(((const float*)w_qkv)[i]);
    } else if (i < 262144) {
        int j = i - 196608;
        wprojB[j] = isBf ? ((const ushortT*)w_proj)[j] : f2bf(((const float*)w_proj)[j]);
    } else if (i < 262912) {
        int j = i - 262144;
        bqF[j] = isBf ? bf2f(((const ushortT*)b_qkv)[j]) : ((const float*)b_qkv)[j];
    } else if (i < 263168) {
        int j = i - 262912;
        bpF[j] = isBf ? bf2f(((const ushortT*)b_proj)[j]) : ((const float*)b_proj)[j];
    }
}

// ---------------------------------------------------------------------------
// Transpose+convert (B, 256, 4096) [f32 or bf16] -> (B, 4096, 256) bf16.
// grid (C/64=4, P/64=64, B=8), block 256. Destination lives in d_out (dead
// until the final projection GEMM overwrites every element).
// ---------------------------------------------------------------------------
__global__ __launch_bounds__(256) void transpose_cp(const void* __restrict__ xv,
                                                    ushortT* __restrict__ xT,
                                                    const int* __restrict__ flagp) {
    __shared__ __align__(16) ushortT tile[64][65];
    const int b  = blockIdx.z;
    const int c0 = blockIdx.x * 64;
    const int p0 = blockIdx.y * 64;
    const int t  = threadIdx.x;
    const int isBf = *flagp;

    if (isBf) {
        const ushortT* xb = (const ushortT*)xv + (size_t)b * 256 * 4096;
#pragma unroll
        for (int it = 0; it < 2; it++) {
            int id  = t + it * 256;          // 0..511
            int row = id >> 3;               // c row 0..63
            int c8  = (id & 7) * 8;          // p chunk
            ushort8v v = *(const ushort8v*)(xb + (size_t)(c0 + row) * 4096 + p0 + c8);
#pragma unroll
            for (int j = 0; j < 8; j++) tile[row][c8 + j] = v[j];
        }
    } else {
        const float* xb = (const float*)xv + (size_t)b * 256 * 4096;
#pragma unroll
        for (int it = 0; it < 4; it++) {
            int id  = t + it * 256;          // 0..1023
            int row = id >> 4;               // c row 0..63
            int c4  = (id & 15) * 4;         // p chunk of 4 floats
            float4 v = *(const float4*)(xb + (size_t)(c0 + row) * 4096 + p0 + c4);
            tile[row][c4 + 0] = f2bf(v.x);
            tile[row][c4 + 1] = f2bf(v.y);
            tile[row][c4 + 2] = f2bf(v.z);
            tile[row][c4 + 3] = f2bf(v.w);
        }
    }
    __syncthreads();
    ushortT* xTb = xT + (size_t)b * 4096 * 256;
#pragma unroll
    for (int it = 0; it < 2; it++) {
        int id   = t + it * 256;             // 0..511
        int prow = id >> 3;                  // p row 0..63
        int cc   = (id & 7) * 8;             // c chunk
        ushort8v v;
#pragma unroll
        for (int j = 0; j < 8; j++) v[j] = tile[cc + j][prow];
        *(ushort8v*)(xTb + (size_t)(p0 + prow) * 256 + c0 + cc) = v;
    }
}

// ---------------------------------------------------------------------------
// GEMM  D[m][n] = sum_k A[m][k] * Bt[n][k]  + bias   (bf16 in, fp32 acc)
// A row-major (lda = K), Bt row-major (row stride ldb), D row-major (ldd).
// outMode 0: D is bf16.  outMode 1: D is bf16 if *flagp else fp32.
// 128x128 tile, BK=32, 4 waves each owning a 64x64 quadrant (4x4 MFMA).
// grid: (N/128, M/128, batches); Bt/D batch-strided.
// ---------------------------------------------------------------------------
__global__ __launch_bounds__(256) void gemm_bt(const ushortT* __restrict__ A,
                                               const ushortT* __restrict__ Bt, long long sBb, int ldb,
                                               void* __restrict__ D, long long sDb, int ldd,
                                               const float* __restrict__ bias, int biasAlongM,
                                               int K, int outMode, const int* __restrict__ flagp) {
    __shared__ __align__(16) ushortT Als[128 * 32];
    __shared__ __align__(16) ushortT Bls[128 * 32];

    const int of32 = (outMode == 1) && (*flagp == 0);
    const int bz = blockIdx.z;
    Bt += (size_t)bz * sBb;

    const int n0   = blockIdx.x * 128;
    const int m0   = blockIdx.y * 128;
    const int t    = threadIdx.x;
    const int wv   = t >> 6;
    const int lane = t & 63;
    const int lm   = lane & 15;
    const int quad = lane >> 4;
    const int wm   = wv & 1;     // wave's 64-row quadrant (m)
    const int wn   = wv >> 1;    // wave's 64-col quadrant (n)

    float4v acc[4][4];
#pragma unroll
    for (int i = 0; i < 4; i++)
#pragma unroll
        for (int j = 0; j < 4; j++) { float4v z = {0.f, 0.f, 0.f, 0.f}; acc[i][j] = z; }

    const int nkt = K >> 5;
    for (int kt = 0; kt < nkt; ++kt) {
        __syncthreads();   // previous tile's LDS reads complete before overwrite
#pragma unroll
        for (int j = 0; j < 2; j++) {
            int cid = wv * 128 + j * 64 + lane;   // 16B-chunk id in [0,512)
            int row = cid >> 2;                   // tile row (4 chunks of 8 bf16 per row)
            int c8  = cid & 3;
            const ushortT* ga = A  + (size_t)(m0 + row) * K   + kt * 32 + c8 * 8;
            const ushortT* gb = Bt + (size_t)(n0 + row) * ldb + kt * 32 + c8 * 8;
            ushortT* la = Als + (size_t)(wv * 128 + j * 64) * 8;   // wave-uniform base
            ushortT* lb = Bls + (size_t)(wv * 128 + j * 64) * 8;
            gld_lds16(ga, la);
            gld_lds16(gb, lb);
        }
        asm volatile("s_waitcnt vmcnt(0)" ::: "memory");
        __syncthreads();

        short8 af[4], bfr[4];
#pragma unroll
        for (int i = 0; i < 4; i++)
            af[i] = *(const short8*)&Als[(wm * 64 + i * 16 + lm) * 32 + quad * 8];
#pragma unroll
        for (int j = 0; j < 4; j++)
            bfr[j] = *(const short8*)&Bls[(wn * 64 + j * 16 + lm) * 32 + quad * 8];
#pragma unroll
        for (int i = 0; i < 4; i++)
#pragma unroll
            for (int j = 0; j < 4; j++)
                acc[i][j] = __builtin_amdgcn_mfma_f32_16x16x32_bf16(af[i], bfr[j], acc[i][j], 0, 0, 0);
    }

    // epilogue: C/D layout col = lane&15, row = quad*4 + reg
    float*   Df = (float*)D   + (size_t)bz * sDb;
    ushortT* Dh = (ushortT*)D + (size_t)bz * sDb;
#pragma unroll
    for (int i = 0; i < 4; i++) {
        int r0 = m0 + wm * 64 + i * 16 + quad * 4;
#pragma unroll
        for (int j = 0; j < 4; j++) {
            int c = n0 + wn * 64 + j * 16 + lm;
#pragma unroll
            for (int rg = 0; rg < 4; rg++) {
                int r = r0 + rg;
                float v = acc[i][j][rg] + bias[biasAlongM ? r : c];
                if (of32) Df[(size_t)r * ldd + c] = v;
                else      Dh[(size_t)r * ldd + c] = f2bf(v);
            }
        }
    }
}

// ---------------------------------------------------------------------------
// Multi-dilated 3x3 local attention, IN-PLACE on bf16 qkv.
// qkv pixel-major (B*4096, 768), channel order [q(8x32) k(8x32) v(8x32)].
// Thread (bp,hd) reads only its own q slice and writes only that slice;
// k/v columns (256..767) are never written -> race-free.
// ---------------------------------------------------------------------------
__global__ __launch_bounds__(256) void attn_k(ushortT* qkv) {
    const int tid = blockIdx.x * 256 + threadIdx.x;
    const int hd  = tid & 7;
    const int bp  = tid >> 3;            // b*4096 + p
    const int p   = bp & 4095;
    const int bb  = bp - p;              // b*4096
    const int h   = p >> 6;
    const int w   = p & 63;
    const int dil = (hd & 3) + 1;        // DILATIONS = [1,2,3,4]

    float q[32];
    {
        const ushortT* qp = qkv + (size_t)bp * 768 + hd * 32;
#pragma unroll
        for (int c = 0; c < 4; c++) {
            ushort8v v = *(const ushort8v*)(qp + c * 8);
#pragma unroll
            for (int j = 0; j < 8; j++) q[c * 8 + j] = bf2f(v[j]);
        }
    }

    float lgt[9];
    int   nb[9];
    unsigned vmask = 0;
#pragma unroll
    for (int ii = 0; ii < 3; ii++) {
#pragma unroll
        for (int jj = 0; jj < 3; jj++) {
            int idx = ii * 3 + jj;
            int hh = h + (ii - 1) * dil;
            int ww = w + (jj - 1) * dil;
            bool ok = ((unsigned)hh < 64u) && ((unsigned)ww < 64u);
            int pp = (hh << 6) + ww;
            nb[idx] = pp;
            float l = 0.f;                 // OOB: k is zero-padded -> logit exactly 0
            if (ok) {
                vmask |= (1u << idx);
                const ushortT* kp = qkv + (size_t)(bb + pp) * 768 + 256 + hd * 32;
#pragma unroll
                for (int c = 0; c < 4; c++) {
                    ushort8v v = *(const ushort8v*)(kp + c * 8);
#pragma unroll
                    for (int j = 0; j < 8; j++) l += q[c * 8 + j] * bf2f(v[j]);
                }
                l *= ATT_SCALE;
            }
            lgt[idx] = l;
        }
    }

    float mx = lgt[0];
#pragma unroll
    for (int i = 1; i < 9; i++) mx = fmaxf(mx, lgt[i]);
    float e[9], s = 0.f;
#pragma unroll
    for (int i = 0; i < 9; i++) { e[i] = __expf(lgt[i] - mx); s += e[i]; }
    const float inv = 1.f / s;

    float acc[32];
#pragma unroll
    for (int d = 0; d < 32; d++) acc[d] = 0.f;
#pragma unroll
    for (int idx = 0; idx < 9; idx++) {
        if ((vmask >> idx) & 1u) {        // OOB: v = 0, contributes nothing (e[idx] stays in s)
            float pj = e[idx] * inv;
            const ushortT* vp = qkv + (size_t)(bb + nb[idx]) * 768 + 512 + hd * 32;
#pragma unroll
            for (int c = 0; c < 4; c++) {
                ushort8v v = *(const ushort8v*)(vp + c * 8);
#pragma unroll
                for (int j = 0; j < 8; j++) acc[c * 8 + j] += pj * bf2f(v[j]);
            }
        }
    }

    ushortT* op = qkv + (size_t)bp * 768 + hd * 32;   // overwrite own q slice
#pragma unroll
    for (int c = 0; c < 4; c++) {
        ushort8v v;
#pragma unroll
        for (int j = 0; j < 8; j++) v[j] = f2bf(acc[c * 8 + j]);
        *(ushort8v*)(op + c * 8) = v;
    }
}

// ---------------------------------------------------------------------------
extern "C" void kernel_launch(void* const* d_in, const int* in_sizes, int n_in,
                              void* d_out, int out_size, void* d_ws, size_t ws_size,
                              hipStream_t stream) {
    const void* x      = d_in[0];  // (8,256,64,64)   fp32 or bf16 (probed)
    const void* w_qkv  = d_in[1];  // (768,256)
    const void* b_qkv  = d_in[2];  // (768,)
    const void* w_proj = d_in[3];  // (256,256)
    const void* b_proj = d_in[4];  // (256,)

    // ws layout (all 256B-aligned): flag | bqF | bpF | wqkvB | wprojB | qkv
    char* ws = (char*)d_ws;
    int*     flag   = (int*)ws;                        // 4 B
    float*   bqF    = (float*)(ws + 256);              // 768 f32
    float*   bpF    = (float*)(ws + 3328);             // 256 f32
    ushortT* wqkvB  = (ushortT*)(ws + 4352);           // 196608 bf16
    ushortT* wprojB = (ushortT*)(ws + 397568);         // 65536 bf16
    ushortT* qkv    = (ushortT*)(ws + 528640);         // (32768,768) bf16 = 48 MiB
    ushortT* xT     = (ushortT*)d_out;                 // (32768,256) bf16 scratch in d_out;
                                                       // fully overwritten by the final GEMM

    // 0) probe input dtype
    detect_dtype<<<1, 256, 0, stream>>>((const ushortT*)x, flag);

    // 0b) weights -> bf16, biases -> fp32
    convert_params<<<1028, 256, 0, stream>>>(w_qkv, w_proj, b_qkv, b_proj,
                                             wqkvB, wprojB, bqF, bpF, flag);

    // 1) x (B,C,P) -> xT (B,P,C) bf16
    transpose_cp<<<dim3(4, 64, 8), 256, 0, stream>>>(x, xT, flag);

    // 2) qkv(32768,768) = xT(32768,256) @ w_qkv^T + b_qkv   (bias along n, bf16 out)
    gemm_bt<<<dim3(6, 256, 1), 256, 0, stream>>>(xT, wqkvB, 0, 256,
                                                 qkv, 0, 768, bqF, 0, 256, 0, flag);

    // 3) attention in-place: y overwrites q slice of qkv
    attn_k<<<dim3(1024), 256, 0, stream>>>(qkv);

    // 4) out(b,256,4096) = w_proj @ y(b)^T + b_proj  (bias along m; out dtype per flag)
    //    y rows are qkv rows (stride 768), cols 0..255
    gemm_bt<<<dim3(32, 2, 8), 256, 0, stream>>>(wprojB, qkv, (long long)4096 * 768, 768,
                                                d_out, (long long)256 * 4096, 4096,
                                                bpF, 1, 256, 1, flag);
}

// Round 4
// 199.277 us; speedup vs baseline: 1.3106x; 1.3106x over previous
//
#include <hip/hip_runtime.h>
#include <cstdint>

typedef unsigned short ushortT;
typedef __attribute__((ext_vector_type(8))) short short8;      // 8 bf16 = 4 VGPRs (MFMA A/B frag)
typedef __attribute__((ext_vector_type(8))) unsigned short ushort8v;
typedef __attribute__((ext_vector_type(4))) float float4v;

#define ATT_SCALE 0.17677669529663687f   // 32^-0.5

__device__ inline float bf2f(unsigned short u) {
    union { unsigned int i; float f; } x; x.i = ((unsigned int)u) << 16; return x.f;
}
__device__ inline unsigned short f2bf(float f) {
    union { float f; unsigned int i; } x; x.f = f;
    unsigned int i = x.i;
    i += 0x7fffu + ((i >> 16) & 1u);      // RNE
    return (unsigned short)(i >> 16);
}

__device__ inline void gld_lds16(const ushortT* g, ushortT* l) {
    // async global->LDS, 16B/lane; LDS dest = wave-uniform base + lane*16
    __builtin_amdgcn_global_load_lds((const __attribute__((address_space(1))) void*)g,
                                     (__attribute__((address_space(3))) void*)l, 16, 0, 0);
}

// ---------------------------------------------------------------------------
// Dtype probe: bf16 N(0,1) -> ~100% of ushorts have exp field in [100,140];
// fp32 N(0,1) read as ushorts -> ~58%. flag = 1 (bf16) / 0 (fp32).
// ---------------------------------------------------------------------------
__global__ void detect_dtype(const ushortT* __restrict__ x, int* __restrict__ flag) {
    __shared__ int cnt;
    if (threadIdx.x == 0) cnt = 0;
    __syncthreads();
    int c = 0;
    for (int i = threadIdx.x; i < 4096; i += 256) {
        unsigned e = (x[i] >> 7) & 0xFFu;
        if (e >= 100u && e <= 140u) c++;
    }
    atomicAdd(&cnt, c);
    __syncthreads();
    if (threadIdx.x == 0) *flag = (cnt > 3600) ? 1 : 0;
}

// ---------------------------------------------------------------------------
// Convert weights -> bf16 and biases -> fp32 (source dtype per flag).
// ---------------------------------------------------------------------------
__global__ __launch_bounds__(256) void convert_params(const void* __restrict__ w_qkv,
                                                      const void* __restrict__ w_proj,
                                                      const void* __restrict__ b_qkv,
                                                      const void* __restrict__ b_proj,
                                                      ushortT* __restrict__ wqkvB,
                                                      ushortT* __restrict__ wprojB,
                                                      float* __restrict__ bqF,
                                                      float* __restrict__ bpF,
                                                      const int* __restrict__ flagp) {
    const int isBf = *flagp;
    int i = blockIdx.x * 256 + threadIdx.x;
    if (i < 196608) {
        wqkvB[i] = isBf ? ((const ushortT*)w_qkv)[i] : f2bf(((const float*)w_qkv)[i]);
    } else if (i < 262144) {
        int j = i - 196608;
        wprojB[j] = isBf ? ((const ushortT*)w_proj)[j] : f2bf(((const float*)w_proj)[j]);
    } else if (i < 262912) {
        int j = i - 262144;
        bqF[j] = isBf ? bf2f(((const ushortT*)b_qkv)[j]) : ((const float*)b_qkv)[j];
    } else if (i < 263168) {
        int j = i - 262912;
        bpF[j] = isBf ? bf2f(((const ushortT*)b_proj)[j]) : ((const float*)b_proj)[j];
    }
}

// ---------------------------------------------------------------------------
// Transpose+convert (B, 256, 4096) [f32 or bf16] -> (B, 4096, 256) bf16.
// grid (C/64=4, P/64=64, B=8), block 256. Destination lives in d_out (dead
// until the final projection GEMM overwrites every element).
// ---------------------------------------------------------------------------
__global__ __launch_bounds__(256) void transpose_cp(const void* __restrict__ xv,
                                                    ushortT* __restrict__ xT,
                                                    const int* __restrict__ flagp) {
    __shared__ __align__(16) ushortT tile[64][65];
    const int b  = blockIdx.z;
    const int c0 = blockIdx.x * 64;
    const int p0 = blockIdx.y * 64;
    const int t  = threadIdx.x;
    const int isBf = *flagp;

    if (isBf) {
        const ushortT* xb = (const ushortT*)xv + (size_t)b * 256 * 4096;
#pragma unroll
        for (int it = 0; it < 2; it++) {
            int id  = t + it * 256;          // 0..511
            int row = id >> 3;               // c row 0..63
            int c8  = (id & 7) * 8;          // p chunk
            ushort8v v = *(const ushort8v*)(xb + (size_t)(c0 + row) * 4096 + p0 + c8);
#pragma unroll
            for (int j = 0; j < 8; j++) tile[row][c8 + j] = v[j];
        }
    } else {
        const float* xb = (const float*)xv + (size_t)b * 256 * 4096;
#pragma unroll
        for (int it = 0; it < 4; it++) {
            int id  = t + it * 256;          // 0..1023
            int row = id >> 4;               // c row 0..63
            int c4  = (id & 15) * 4;         // p chunk of 4 floats
            float4 v = *(const float4*)(xb + (size_t)(c0 + row) * 4096 + p0 + c4);
            tile[row][c4 + 0] = f2bf(v.x);
            tile[row][c4 + 1] = f2bf(v.y);
            tile[row][c4 + 2] = f2bf(v.z);
            tile[row][c4 + 3] = f2bf(v.w);
        }
    }
    __syncthreads();
    ushortT* xTb = xT + (size_t)b * 4096 * 256;
#pragma unroll
    for (int it = 0; it < 2; it++) {
        int id   = t + it * 256;             // 0..511
        int prow = id >> 3;                  // p row 0..63
        int cc   = (id & 7) * 8;             // c chunk
        ushort8v v;
#pragma unroll
        for (int j = 0; j < 8; j++) v[j] = tile[cc + j][prow];
        *(ushort8v*)(xTb + (size_t)(p0 + prow) * 256 + c0 + cc) = v;
    }
}

// ---------------------------------------------------------------------------
// GEMM  D[m][n] = sum_k A[m][k] * Bt[n][k]  + bias   (bf16 in, fp32 acc)
// A row-major (lda = K).
// B: bHeadMajor=0 -> row-major (row stride ldb);
//    bHeadMajor=1 -> head-major: Bt[((k>>5)*32768 + n)*32 + (k&31)]  (BK=32
//    aligns with the 32-ch groups, so group index == kt).
// D: dHeadMajor=1 -> bf16 head-major D[((c>>5)*32768 + r)*32 + (c&31)];
//    else row-major (ldd), bf16 or fp32 per (outMode==1 && !*flagp).
// 128x128 tile, BK=32, 4 waves each owning a 64x64 quadrant (4x4 MFMA).
// grid: (N/128, M/128, batches); Bt/D batch-strided (sBb/sDb elements).
// ---------------------------------------------------------------------------
__global__ __launch_bounds__(256) void gemm_bt(const ushortT* __restrict__ A,
                                               const ushortT* __restrict__ Bt, long long sBb,
                                               int ldb, int bHeadMajor,
                                               void* __restrict__ D, long long sDb,
                                               int ldd, int dHeadMajor,
                                               const float* __restrict__ bias, int biasAlongM,
                                               int K, int outMode, const int* __restrict__ flagp) {
    __shared__ __align__(16) ushortT Als[128 * 32];
    __shared__ __align__(16) ushortT Bls[128 * 32];

    const int of32 = (outMode == 1) && (*flagp == 0);
    const int bz = blockIdx.z;
    Bt += (size_t)bz * sBb;

    const int n0   = blockIdx.x * 128;
    const int m0   = blockIdx.y * 128;
    const int t    = threadIdx.x;
    const int wv   = t >> 6;
    const int lane = t & 63;
    const int lm   = lane & 15;
    const int quad = lane >> 4;
    const int wm   = wv & 1;     // wave's 64-row quadrant (m)
    const int wn   = wv >> 1;    // wave's 64-col quadrant (n)

    float4v acc[4][4];
#pragma unroll
    for (int i = 0; i < 4; i++)
#pragma unroll
        for (int j = 0; j < 4; j++) { float4v z = {0.f, 0.f, 0.f, 0.f}; acc[i][j] = z; }

    const int nkt = K >> 5;
    for (int kt = 0; kt < nkt; ++kt) {
        __syncthreads();   // previous tile's LDS reads complete before overwrite
#pragma unroll
        for (int j = 0; j < 2; j++) {
            int cid = wv * 128 + j * 64 + lane;   // 16B-chunk id in [0,512)
            int row = cid >> 2;                   // tile row (4 chunks of 8 bf16 per row)
            int c8  = cid & 3;
            const ushortT* ga = A + (size_t)(m0 + row) * K + kt * 32 + c8 * 8;
            const ushortT* gb = bHeadMajor
                ? Bt + ((size_t)kt * 32768 + (n0 + row)) * 32 + c8 * 8
                : Bt + (size_t)(n0 + row) * ldb + kt * 32 + c8 * 8;
            ushortT* la = Als + (size_t)(wv * 128 + j * 64) * 8;   // wave-uniform base
            ushortT* lb = Bls + (size_t)(wv * 128 + j * 64) * 8;
            gld_lds16(ga, la);
            gld_lds16(gb, lb);
        }
        asm volatile("s_waitcnt vmcnt(0)" ::: "memory");
        __syncthreads();

        short8 af[4], bfr[4];
#pragma unroll
        for (int i = 0; i < 4; i++)
            af[i] = *(const short8*)&Als[(wm * 64 + i * 16 + lm) * 32 + quad * 8];
#pragma unroll
        for (int j = 0; j < 4; j++)
            bfr[j] = *(const short8*)&Bls[(wn * 64 + j * 16 + lm) * 32 + quad * 8];
#pragma unroll
        for (int i = 0; i < 4; i++)
#pragma unroll
            for (int j = 0; j < 4; j++)
                acc[i][j] = __builtin_amdgcn_mfma_f32_16x16x32_bf16(af[i], bfr[j], acc[i][j], 0, 0, 0);
    }

    // epilogue: C/D layout col = lane&15, row = quad*4 + reg
    float*   Df = (float*)D   + (size_t)bz * sDb;
    ushortT* Dh = (ushortT*)D + (size_t)bz * sDb;
#pragma unroll
    for (int i = 0; i < 4; i++) {
        int r0 = m0 + wm * 64 + i * 16 + quad * 4;
#pragma unroll
        for (int j = 0; j < 4; j++) {
            int c = n0 + wn * 64 + j * 16 + lm;
#pragma unroll
            for (int rg = 0; rg < 4; rg++) {
                int r = r0 + rg;
                float v = acc[i][j][rg] + bias[biasAlongM ? r : c];
                if (dHeadMajor)
                    Dh[((size_t)(c >> 5) * 32768 + r) * 32 + (c & 31)] = f2bf(v);
                else if (of32)
                    Df[(size_t)r * ldd + c] = v;
                else
                    Dh[(size_t)r * ldd + c] = f2bf(v);
            }
        }
    }
}

// ---------------------------------------------------------------------------
// Multi-dilated 3x3 local attention, IN-PLACE on HEAD-MAJOR bf16 qkv:
// qkv[(part*8+hd)*32768 + bp][32], part in {q,k,v}.
// One wave = 64 consecutive pixels (one image row) of ONE head -> all q/k/v
// loads are contiguous 4KB/wave segments; hh bounds are wave-uniform.
// Thread writes only its own q slice (k/v never written) -> race-free.
// ---------------------------------------------------------------------------
__global__ __launch_bounds__(256) void attn_k(ushortT* qkv) {
    const int gt   = blockIdx.x * 256 + threadIdx.x;
    const int lane = gt & 63;
    const int wid  = gt >> 6;          // 0..4095
    const int hd   = wid >> 9;         // 0..7  (512 waves per head)
    const int rowI = wid & 511;        // b*64 + h
    const int b    = rowI >> 6;
    const int h    = rowI & 63;
    const int w    = lane;
    const int dil  = (hd & 3) + 1;     // DILATIONS = [1,2,3,4]
    const int bp   = b * 4096 + h * 64 + w;

    ushortT*       qp    = qkv + ((size_t)hd * 32768 + bp) * 32;
    const ushortT* kbase = qkv + ((size_t)(8  + hd) * 32768 + (size_t)b * 4096) * 32;
    const ushortT* vbase = qkv + ((size_t)(16 + hd) * 32768 + (size_t)b * 4096) * 32;

    float q[32];
#pragma unroll
    for (int c = 0; c < 4; c++) {
        ushort8v v = *(const ushort8v*)(qp + c * 8);
#pragma unroll
        for (int j = 0; j < 8; j++) q[c * 8 + j] = bf2f(v[j]);
    }

    float lgt[9];
    int   nb[9];
    unsigned vmask = 0;
#pragma unroll
    for (int ii = 0; ii < 3; ii++) {
#pragma unroll
        for (int jj = 0; jj < 3; jj++) {
            int idx = ii * 3 + jj;
            int hh = h + (ii - 1) * dil;   // wave-uniform
            int ww = w + (jj - 1) * dil;
            bool ok = ((unsigned)hh < 64u) && ((unsigned)ww < 64u);
            int pp = (hh << 6) + ww;
            nb[idx] = pp;
            float l = 0.f;                 // OOB: k is zero-padded -> logit exactly 0
            if (ok) {
                vmask |= (1u << idx);
                const ushortT* kp = kbase + (size_t)pp * 32;
#pragma unroll
                for (int c = 0; c < 4; c++) {
                    ushort8v v = *(const ushort8v*)(kp + c * 8);
#pragma unroll
                    for (int j = 0; j < 8; j++) l += q[c * 8 + j] * bf2f(v[j]);
                }
                l *= ATT_SCALE;
            }
            lgt[idx] = l;
        }
    }

    float mx = lgt[0];
#pragma unroll
    for (int i = 1; i < 9; i++) mx = fmaxf(mx, lgt[i]);
    float e[9], s = 0.f;
#pragma unroll
    for (int i = 0; i < 9; i++) { e[i] = __expf(lgt[i] - mx); s += e[i]; }
    const float inv = 1.f / s;

    float acc[32];
#pragma unroll
    for (int d = 0; d < 32; d++) acc[d] = 0.f;
#pragma unroll
    for (int idx = 0; idx < 9; idx++) {
        if ((vmask >> idx) & 1u) {        // OOB: v = 0, contributes nothing (e[idx] stays in s)
            float pj = e[idx] * inv;
            const ushortT* vp = vbase + (size_t)nb[idx] * 32;
#pragma unroll
            for (int c = 0; c < 4; c++) {
                ushort8v v = *(const ushort8v*)(vp + c * 8);
#pragma unroll
                for (int j = 0; j < 8; j++) acc[c * 8 + j] += pj * bf2f(v[j]);
            }
        }
    }

#pragma unroll
    for (int c = 0; c < 4; c++) {         // overwrite own q slice
        ushort8v v;
#pragma unroll
        for (int j = 0; j < 8; j++) v[j] = f2bf(acc[c * 8 + j]);
        *(ushort8v*)(qp + c * 8) = v;
    }
}

// ---------------------------------------------------------------------------
extern "C" void kernel_launch(void* const* d_in, const int* in_sizes, int n_in,
                              void* d_out, int out_size, void* d_ws, size_t ws_size,
                              hipStream_t stream) {
    const void* x      = d_in[0];  // (8,256,64,64)   fp32 or bf16 (probed)
    const void* w_qkv  = d_in[1];  // (768,256)
    const void* b_qkv  = d_in[2];  // (768,)
    const void* w_proj = d_in[3];  // (256,256)
    const void* b_proj = d_in[4];  // (256,)

    // ws layout (256B-aligned): flag | bqF | bpF | wqkvB | wprojB | qkv(head-major)
    char* ws = (char*)d_ws;
    int*     flag   = (int*)ws;                        // 4 B
    float*   bqF    = (float*)(ws + 256);              // 768 f32
    float*   bpF    = (float*)(ws + 3328);             // 256 f32
    ushortT* wqkvB  = (ushortT*)(ws + 4352);           // 196608 bf16
    ushortT* wprojB = (ushortT*)(ws + 397568);         // 65536 bf16
    ushortT* qkv    = (ushortT*)(ws + 528640);         // 24 x 32768 x 32 bf16 = 48 MiB
    ushortT* xT     = (ushortT*)d_out;                 // (32768,256) bf16 scratch in d_out;
                                                       // fully overwritten by the final GEMM

    // 0) probe input dtype
    detect_dtype<<<1, 256, 0, stream>>>((const ushortT*)x, flag);

    // 0b) weights -> bf16, biases -> fp32
    convert_params<<<1028, 256, 0, stream>>>(w_qkv, w_proj, b_qkv, b_proj,
                                             wqkvB, wprojB, bqF, bpF, flag);

    // 1) x (B,C,P) -> xT (B,P,C) bf16
    transpose_cp<<<dim3(4, 64, 8), 256, 0, stream>>>(x, xT, flag);

    // 2) qkv head-major = xT(32768,256) @ w_qkv^T + b_qkv   (bias along n)
    gemm_bt<<<dim3(6, 256, 1), 256, 0, stream>>>(xT, wqkvB, 0, 256, 0,
                                                 qkv, 0, 0, 1,
                                                 bqF, 0, 256, 0, flag);

    // 3) attention in-place on head-major qkv (y overwrites q slices)
    attn_k<<<dim3(1024), 256, 0, stream>>>(qkv);

    // 4) out(b,256,4096) = w_proj @ y(b)^T + b_proj  (bias along m; out dtype per flag)
    //    y = q-slices of head-major qkv; batch stride = 4096*32 elements
    gemm_bt<<<dim3(32, 2, 8), 256, 0, stream>>>(wprojB, qkv, (long long)4096 * 32, 0, 1,
                                                d_out, (long long)256 * 4096, 4096, 0,
                                                bpF, 1, 256, 1, flag);
}

// Round 5
// 189.090 us; speedup vs baseline: 1.3812x; 1.0539x over previous
//
#include <hip/hip_runtime.h>
#include <cstdint>

typedef unsigned short ushortT;
typedef __attribute__((ext_vector_type(8))) short short8;      // 8 bf16 = 4 VGPRs (MFMA A/B frag)
typedef __attribute__((ext_vector_type(8))) unsigned short ushort8v;
typedef __attribute__((ext_vector_type(4))) float float4v;

#define ATT_SCALE 0.17677669529663687f   // 32^-0.5

__device__ inline float bf2f(unsigned short u) {
    union { unsigned int i; float f; } x; x.i = ((unsigned int)u) << 16; return x.f;
}
__device__ inline unsigned short f2bf(float f) {
    union { float f; unsigned int i; } x; x.f = f;
    unsigned int i = x.i;
    i += 0x7fffu + ((i >> 16) & 1u);      // RNE
    return (unsigned short)(i >> 16);
}

__device__ inline void gld_lds16(const ushortT* g, ushortT* l) {
    // async global->LDS, 16B/lane; LDS dest = wave-uniform base + lane*16
    __builtin_amdgcn_global_load_lds((const __attribute__((address_space(1))) void*)g,
                                     (__attribute__((address_space(3))) void*)l, 16, 0, 0);
}

// ---------------------------------------------------------------------------
// Dtype probe: bf16 N(0,1) -> ~100% of ushorts have exp field in [100,140];
// fp32 N(0,1) read as ushorts -> ~58%. flag = 1 (bf16) / 0 (fp32).
// ---------------------------------------------------------------------------
__global__ void detect_dtype(const ushortT* __restrict__ x, int* __restrict__ flag) {
    __shared__ int cnt;
    if (threadIdx.x == 0) cnt = 0;
    __syncthreads();
    int c = 0;
    for (int i = threadIdx.x; i < 4096; i += 256) {
        unsigned e = (x[i] >> 7) & 0xFFu;
        if (e >= 100u && e <= 140u) c++;
    }
    atomicAdd(&cnt, c);
    __syncthreads();
    if (threadIdx.x == 0) *flag = (cnt > 3600) ? 1 : 0;
}

// ---------------------------------------------------------------------------
// Convert weights -> bf16 and biases -> fp32 (source dtype per flag).
// ---------------------------------------------------------------------------
__global__ __launch_bounds__(256) void convert_params(const void* __restrict__ w_qkv,
                                                      const void* __restrict__ w_proj,
                                                      const void* __restrict__ b_qkv,
                                                      const void* __restrict__ b_proj,
                                                      ushortT* __restrict__ wqkvB,
                                                      ushortT* __restrict__ wprojB,
                                                      float* __restrict__ bqF,
                                                      float* __restrict__ bpF,
                                                      const int* __restrict__ flagp) {
    const int isBf = *flagp;
    int i = blockIdx.x * 256 + threadIdx.x;
    if (i < 196608) {
        wqkvB[i] = isBf ? ((const ushortT*)w_qkv)[i] : f2bf(((const float*)w_qkv)[i]);
    } else if (i < 262144) {
        int j = i - 196608;
        wprojB[j] = isBf ? ((const ushortT*)w_proj)[j] : f2bf(((const float*)w_proj)[j]);
    } else if (i < 262912) {
        int j = i - 262144;
        bqF[j] = isBf ? bf2f(((const ushortT*)b_qkv)[j]) : ((const float*)b_qkv)[j];
    } else if (i < 263168) {
        int j = i - 262912;
        bpF[j] = isBf ? bf2f(((const ushortT*)b_proj)[j]) : ((const float*)b_proj)[j];
    }
}

// ---------------------------------------------------------------------------
// Transpose+convert (B, 256, 4096) [f32 or bf16] -> (B, 4096, 256) bf16.
// grid (C/64=4, P/64=64, B=8), block 256. Destination lives in d_out (dead
// until the final projection GEMM overwrites every element).
// ---------------------------------------------------------------------------
__global__ __launch_bounds__(256) void transpose_cp(const void* __restrict__ xv,
                                                    ushortT* __restrict__ xT,
                                                    const int* __restrict__ flagp) {
    __shared__ __align__(16) ushortT tile[64][65];
    const int b  = blockIdx.z;
    const int c0 = blockIdx.x * 64;
    const int p0 = blockIdx.y * 64;
    const int t  = threadIdx.x;
    const int isBf = *flagp;

    if (isBf) {
        const ushortT* xb = (const ushortT*)xv + (size_t)b * 256 * 4096;
#pragma unroll
        for (int it = 0; it < 2; it++) {
            int id  = t + it * 256;          // 0..511
            int row = id >> 3;               // c row 0..63
            int c8  = (id & 7) * 8;          // p chunk
            ushort8v v = *(const ushort8v*)(xb + (size_t)(c0 + row) * 4096 + p0 + c8);
#pragma unroll
            for (int j = 0; j < 8; j++) tile[row][c8 + j] = v[j];
        }
    } else {
        const float* xb = (const float*)xv + (size_t)b * 256 * 4096;
#pragma unroll
        for (int it = 0; it < 4; it++) {
            int id  = t + it * 256;          // 0..1023
            int row = id >> 4;               // c row 0..63
            int c4  = (id & 15) * 4;         // p chunk of 4 floats
            float4 v = *(const float4*)(xb + (size_t)(c0 + row) * 4096 + p0 + c4);
            tile[row][c4 + 0] = f2bf(v.x);
            tile[row][c4 + 1] = f2bf(v.y);
            tile[row][c4 + 2] = f2bf(v.z);
            tile[row][c4 + 3] = f2bf(v.w);
        }
    }
    __syncthreads();
    ushortT* xTb = xT + (size_t)b * 4096 * 256;
#pragma unroll
    for (int it = 0; it < 2; it++) {
        int id   = t + it * 256;             // 0..511
        int prow = id >> 3;                  // p row 0..63
        int cc   = (id & 7) * 8;             // c chunk
        ushort8v v;
#pragma unroll
        for (int j = 0; j < 8; j++) v[j] = tile[cc + j][prow];
        *(ushort8v*)(xTb + (size_t)(p0 + prow) * 256 + c0 + cc) = v;
    }
}

// ---------------------------------------------------------------------------
// GEMM  D[m][n] = sum_k A[m][k] * Bt[n][k]  + bias   (bf16 in, fp32 acc)
// A row-major (lda = K).
// B: bHeadMajor=0 -> row-major (row stride ldb);
//    bHeadMajor=1 -> head-major: Bt[((k>>5)*32768 + n)*32 + (k&31)].
// D: dHeadMajor=1 -> bf16 head-major D[((c>>5)*32768 + r)*32 + (c&31)],
//      written via LDS restage as fully-coalesced 16B stores (a 32-ch group
//      x 128 rows is one contiguous 8KB region);
//    else row-major (ldd), bf16 or fp32 per (outMode==1 && !*flagp).
// LDS tiles are XOR-chunk-swizzled: global chunk c8^((row>>1)&3) lands in
// physical slot c8, so frag reads at slot quad^((r>>1)&3) hit 8 bank-quads
// (2-way, free) instead of 2 (4-way).
// 128x128 tile, BK=32, 4 waves each owning a 64x64 quadrant (4x4 MFMA).
// grid: (N/128, M/128, batches); Bt/D batch-strided (sBb/sDb elements).
// ---------------------------------------------------------------------------
__global__ __launch_bounds__(256) void gemm_bt(const ushortT* __restrict__ A,
                                               const ushortT* __restrict__ Bt, long long sBb,
                                               int ldb, int bHeadMajor,
                                               void* __restrict__ D, long long sDb,
                                               int ldd, int dHeadMajor,
                                               const float* __restrict__ bias, int biasAlongM,
                                               int K, int outMode, const int* __restrict__ flagp) {
    __shared__ __align__(16) ushortT pool[16384];   // 32 KB: main loop uses 16 KB; epilogue all
    ushortT* Als = pool;            // 128*32
    ushortT* Bls = pool + 4096;     // 128*32

    const int of32 = (outMode == 1) && (*flagp == 0);
    const int bz = blockIdx.z;
    Bt += (size_t)bz * sBb;

    const int n0   = blockIdx.x * 128;
    const int m0   = blockIdx.y * 128;
    const int t    = threadIdx.x;
    const int wv   = t >> 6;
    const int lane = t & 63;
    const int lm   = lane & 15;
    const int quad = lane >> 4;
    const int wm   = wv & 1;     // wave's 64-row quadrant (m)
    const int wn   = wv >> 1;    // wave's 64-col quadrant (n)

    float4v acc[4][4];
#pragma unroll
    for (int i = 0; i < 4; i++)
#pragma unroll
        for (int j = 0; j < 4; j++) { float4v z = {0.f, 0.f, 0.f, 0.f}; acc[i][j] = z; }

    const int nkt = K >> 5;
    for (int kt = 0; kt < nkt; ++kt) {
        __syncthreads();   // previous tile's LDS reads complete before overwrite
#pragma unroll
        for (int j = 0; j < 2; j++) {
            int cid = wv * 128 + j * 64 + lane;   // 16B-chunk id in [0,512)
            int row = cid >> 2;                   // tile row (4 chunks of 8 bf16 per row)
            int c8  = cid & 3;
            int gc  = c8 ^ ((row >> 1) & 3);      // swizzled global chunk (same 64B segment)
            const ushortT* ga = A + (size_t)(m0 + row) * K + kt * 32 + gc * 8;
            const ushortT* gb = bHeadMajor
                ? Bt + ((size_t)kt * 32768 + (n0 + row)) * 32 + gc * 8
                : Bt + (size_t)(n0 + row) * ldb + kt * 32 + gc * 8;
            ushortT* la = Als + (size_t)(wv * 128 + j * 64) * 8;   // wave-uniform base
            ushortT* lb = Bls + (size_t)(wv * 128 + j * 64) * 8;
            gld_lds16(ga, la);
            gld_lds16(gb, lb);
        }
        asm volatile("s_waitcnt vmcnt(0)" ::: "memory");
        __syncthreads();

        short8 af[4], bfr[4];
#pragma unroll
        for (int i = 0; i < 4; i++) {
            int r = wm * 64 + i * 16 + lm;
            int slot = quad ^ ((r >> 1) & 3);
            af[i] = *(const short8*)&Als[r * 32 + slot * 8];
        }
#pragma unroll
        for (int j = 0; j < 4; j++) {
            int r = wn * 64 + j * 16 + lm;
            int slot = quad ^ ((r >> 1) & 3);
            bfr[j] = *(const short8*)&Bls[r * 32 + slot * 8];
        }
#pragma unroll
        for (int i = 0; i < 4; i++)
#pragma unroll
            for (int j = 0; j < 4; j++)
                acc[i][j] = __builtin_amdgcn_mfma_f32_16x16x32_bf16(af[i], bfr[j], acc[i][j], 0, 0, 0);
    }

    // epilogue: C/D layout col = lane&15, row = quad*4 + reg
    if (dHeadMajor) {
        // Stage 128x128 bf16 tile in LDS (chunk-XOR swizzle on (r&7)), then
        // write 4 groups x 8KB fully-contiguous with ushort8 stores.
        __syncthreads();   // all frag reads done before pool overwrite
#pragma unroll
        for (int i = 0; i < 4; i++) {
#pragma unroll
            for (int j = 0; j < 4; j++) {
                int c = wn * 64 + j * 16 + lm;
#pragma unroll
                for (int rg = 0; rg < 4; rg++) {
                    int r = wm * 64 + i * 16 + quad * 4 + rg;
                    float v = acc[i][j][rg] + bias[biasAlongM ? (m0 + r) : (n0 + c)];
                    int chunk = (c >> 3) ^ (r & 7);
                    pool[r * 128 + chunk * 8 + (c & 7)] = f2bf(v);
                }
            }
        }
        __syncthreads();
        ushortT* Dh = (ushortT*)D + (size_t)bz * sDb;
#pragma unroll
        for (int g = 0; g < 4; g++) {
            ushortT* base = Dh + ((size_t)((n0 >> 5) + g) * 32768 + m0) * 32;
#pragma unroll
            for (int it = 0; it < 2; it++) {
                int id = it * 256 + t;          // 0..511
                int r  = id >> 2;
                int cb = id & 3;                // 8-chunk within group
                int pch = (g * 4 + cb) ^ (r & 7);
                ushort8v v = *(const ushort8v*)&pool[r * 128 + pch * 8];
                *(ushort8v*)(base + r * 32 + cb * 8) = v;
            }
        }
    } else {
        float*   Df = (float*)D   + (size_t)bz * sDb;
        ushortT* Dh = (ushortT*)D + (size_t)bz * sDb;
#pragma unroll
        for (int i = 0; i < 4; i++) {
            int r0 = m0 + wm * 64 + i * 16 + quad * 4;
#pragma unroll
            for (int j = 0; j < 4; j++) {
                int c = n0 + wn * 64 + j * 16 + lm;
#pragma unroll
                for (int rg = 0; rg < 4; rg++) {
                    int r = r0 + rg;
                    float v = acc[i][j][rg] + bias[biasAlongM ? r : c];
                    if (of32) Df[(size_t)r * ldd + c] = v;
                    else      Dh[(size_t)r * ldd + c] = f2bf(v);
                }
            }
        }
    }
}

// ---------------------------------------------------------------------------
// Multi-dilated 3x3 local attention, IN-PLACE on HEAD-MAJOR bf16 qkv:
// qkv[(part*8+hd)*32768 + bp][32], part in {q,k,v}.
// One wave = 64 consecutive pixels (one image row) of ONE head -> all q/k/v
// loads are contiguous 4KB/wave segments; hh bounds are wave-uniform.
// Thread writes only its own q slice (k/v never written) -> race-free.
// ---------------------------------------------------------------------------
__global__ __launch_bounds__(256) void attn_k(ushortT* qkv) {
    const int gt   = blockIdx.x * 256 + threadIdx.x;
    const int lane = gt & 63;
    const int wid  = gt >> 6;          // 0..4095
    const int hd   = wid >> 9;         // 0..7  (512 waves per head)
    const int rowI = wid & 511;        // b*64 + h
    const int b    = rowI >> 6;
    const int h    = rowI & 63;
    const int w    = lane;
    const int dil  = (hd & 3) + 1;     // DILATIONS = [1,2,3,4]
    const int bp   = b * 4096 + h * 64 + w;

    ushortT*       qp    = qkv + ((size_t)hd * 32768 + bp) * 32;
    const ushortT* kbase = qkv + ((size_t)(8  + hd) * 32768 + (size_t)b * 4096) * 32;
    const ushortT* vbase = qkv + ((size_t)(16 + hd) * 32768 + (size_t)b * 4096) * 32;

    float q[32];
#pragma unroll
    for (int c = 0; c < 4; c++) {
        ushort8v v = *(const ushort8v*)(qp + c * 8);
#pragma unroll
        for (int j = 0; j < 8; j++) q[c * 8 + j] = bf2f(v[j]);
    }

    float lgt[9];
    int   nb[9];
    unsigned vmask = 0;
#pragma unroll
    for (int ii = 0; ii < 3; ii++) {
#pragma unroll
        for (int jj = 0; jj < 3; jj++) {
            int idx = ii * 3 + jj;
            int hh = h + (ii - 1) * dil;   // wave-uniform
            int ww = w + (jj - 1) * dil;
            bool ok = ((unsigned)hh < 64u) && ((unsigned)ww < 64u);
            int pp = (hh << 6) + ww;
            nb[idx] = pp;
            float l = 0.f;                 // OOB: k is zero-padded -> logit exactly 0
            if (ok) {
                vmask |= (1u << idx);
                const ushortT* kp = kbase + (size_t)pp * 32;
#pragma unroll
                for (int c = 0; c < 4; c++) {
                    ushort8v v = *(const ushort8v*)(kp + c * 8);
#pragma unroll
                    for (int j = 0; j < 8; j++) l += q[c * 8 + j] * bf2f(v[j]);
                }
                l *= ATT_SCALE;
            }
            lgt[idx] = l;
        }
    }

    float mx = lgt[0];
#pragma unroll
    for (int i = 1; i < 9; i++) mx = fmaxf(mx, lgt[i]);
    float e[9], s = 0.f;
#pragma unroll
    for (int i = 0; i < 9; i++) { e[i] = __expf(lgt[i] - mx); s += e[i]; }
    const float inv = 1.f / s;

    float acc[32];
#pragma unroll
    for (int d = 0; d < 32; d++) acc[d] = 0.f;
#pragma unroll
    for (int idx = 0; idx < 9; idx++) {
        if ((vmask >> idx) & 1u) {        // OOB: v = 0, contributes nothing (e[idx] stays in s)
            float pj = e[idx] * inv;
            const ushortT* vp = vbase + (size_t)nb[idx] * 32;
#pragma unroll
            for (int c = 0; c < 4; c++) {
                ushort8v v = *(const ushort8v*)(vp + c * 8);
#pragma unroll
                for (int j = 0; j < 8; j++) acc[c * 8 + j] += pj * bf2f(v[j]);
            }
        }
    }

#pragma unroll
    for (int c = 0; c < 4; c++) {         // overwrite own q slice
        ushort8v v;
#pragma unroll
        for (int j = 0; j < 8; j++) v[j] = f2bf(acc[c * 8 + j]);
        *(ushort8v*)(qp + c * 8) = v;
    }
}

// ---------------------------------------------------------------------------
extern "C" void kernel_launch(void* const* d_in, const int* in_sizes, int n_in,
                              void* d_out, int out_size, void* d_ws, size_t ws_size,
                              hipStream_t stream) {
    const void* x      = d_in[0];  // (8,256,64,64)   fp32 or bf16 (probed)
    const void* w_qkv  = d_in[1];  // (768,256)
    const void* b_qkv  = d_in[2];  // (768,)
    const void* w_proj = d_in[3];  // (256,256)
    const void* b_proj = d_in[4];  // (256,)

    // ws layout (256B-aligned): flag | bqF | bpF | wqkvB | wprojB | qkv(head-major)
    char* ws = (char*)d_ws;
    int*     flag   = (int*)ws;                        // 4 B
    float*   bqF    = (float*)(ws + 256);              // 768 f32
    float*   bpF    = (float*)(ws + 3328);             // 256 f32
    ushortT* wqkvB  = (ushortT*)(ws + 4352);           // 196608 bf16
    ushortT* wprojB = (ushortT*)(ws + 397568);         // 65536 bf16
    ushortT* qkv    = (ushortT*)(ws + 528640);         // 24 x 32768 x 32 bf16 = 48 MiB
    ushortT* xT     = (ushortT*)d_out;                 // (32768,256) bf16 scratch in d_out;
                                                       // fully overwritten by the final GEMM

    // 0) probe input dtype
    detect_dtype<<<1, 256, 0, stream>>>((const ushortT*)x, flag);

    // 0b) weights -> bf16, biases -> fp32
    convert_params<<<1028, 256, 0, stream>>>(w_qkv, w_proj, b_qkv, b_proj,
                                             wqkvB, wprojB, bqF, bpF, flag);

    // 1) x (B,C,P) -> xT (B,P,C) bf16
    transpose_cp<<<dim3(4, 64, 8), 256, 0, stream>>>(x, xT, flag);

    // 2) qkv head-major = xT(32768,256) @ w_qkv^T + b_qkv   (bias along n)
    gemm_bt<<<dim3(6, 256, 1), 256, 0, stream>>>(xT, wqkvB, 0, 256, 0,
                                                 qkv, 0, 0, 1,
                                                 bqF, 0, 256, 0, flag);

    // 3) attention in-place on head-major qkv (y overwrites q slices)
    attn_k<<<dim3(1024), 256, 0, stream>>>(qkv);

    // 4) out(b,256,4096) = w_proj @ y(b)^T + b_proj  (bias along m; out dtype per flag)
    //    y = q-slices of head-major qkv; batch stride = 4096*32 elements
    gemm_bt<<<dim3(32, 2, 8), 256, 0, stream>>>(wprojB, qkv, (long long)4096 * 32, 0, 1,
                                                d_out, (long long)256 * 4096, 4096, 0,
                                                bpF, 1, 256, 1, flag);
}

// Round 6
// 182.810 us; speedup vs baseline: 1.4287x; 1.0343x over previous
//
#include <hip/hip_runtime.h>
#include <cstdint>

typedef unsigned short ushortT;
typedef __attribute__((ext_vector_type(8))) short short8;      // 8 bf16 = 4 VGPRs (MFMA A/B frag)
typedef __attribute__((ext_vector_type(8))) unsigned short ushort8v;
typedef __attribute__((ext_vector_type(4))) float float4v;

#define ATT_SCALE 0.17677669529663687f   // 32^-0.5

__device__ inline float bf2f(unsigned short u) {
    union { unsigned int i; float f; } x; x.i = ((unsigned int)u) << 16; return x.f;
}
__device__ inline unsigned short f2bf(float f) {
    union { float f; unsigned int i; } x; x.f = f;
    unsigned int i = x.i;
    i += 0x7fffu + ((i >> 16) & 1u);      // RNE
    return (unsigned short)(i >> 16);
}

__device__ inline void gld_lds16(const ushortT* g, ushortT* l) {
    // async global->LDS, 16B/lane; LDS dest = wave-uniform base + lane*16
    __builtin_amdgcn_global_load_lds((const __attribute__((address_space(1))) void*)g,
                                     (__attribute__((address_space(3))) void*)l, 16, 0, 0);
}

// ---------------------------------------------------------------------------
// Dtype probe: bf16 N(0,1) -> ~100% of ushorts have exp field in [100,140];
// fp32 N(0,1) read as ushorts -> ~58%. flag = 1 (bf16) / 0 (fp32).
// ---------------------------------------------------------------------------
__global__ void detect_dtype(const ushortT* __restrict__ x, int* __restrict__ flag) {
    __shared__ int cnt;
    if (threadIdx.x == 0) cnt = 0;
    __syncthreads();
    int c = 0;
    for (int i = threadIdx.x; i < 4096; i += 256) {
        unsigned e = (x[i] >> 7) & 0xFFu;
        if (e >= 100u && e <= 140u) c++;
    }
    atomicAdd(&cnt, c);
    __syncthreads();
    if (threadIdx.x == 0) *flag = (cnt > 3600) ? 1 : 0;
}

// ---------------------------------------------------------------------------
// Convert weights -> bf16 and biases -> fp32 (source dtype per flag).
// ---------------------------------------------------------------------------
__global__ __launch_bounds__(256) void convert_params(const void* __restrict__ w_qkv,
                                                      const void* __restrict__ w_proj,
                                                      const void* __restrict__ b_qkv,
                                                      const void* __restrict__ b_proj,
                                                      ushortT* __restrict__ wqkvB,
                                                      ushortT* __restrict__ wprojB,
                                                      float* __restrict__ bqF,
                                                      float* __restrict__ bpF,
                                                      const int* __restrict__ flagp) {
    const int isBf = *flagp;
    int i = blockIdx.x * 256 + threadIdx.x;
    if (i < 196608) {
        wqkvB[i] = isBf ? ((const ushortT*)w_qkv)[i] : f2bf(((const float*)w_qkv)[i]);
    } else if (i < 262144) {
        int j = i - 196608;
        wprojB[j] = isBf ? ((const ushortT*)w_proj)[j] : f2bf(((const float*)w_proj)[j]);
    } else if (i < 262912) {
        int j = i - 262144;
        bqF[j] = isBf ? bf2f(((const ushortT*)b_qkv)[j]) : ((const float*)b_qkv)[j];
    } else if (i < 263168) {
        int j = i - 262912;
        bpF[j] = isBf ? bf2f(((const ushortT*)b_proj)[j]) : ((const float*)b_proj)[j];
    }
}

// ---------------------------------------------------------------------------
// Transpose+convert (B, 256, 4096) [f32 or bf16] -> (B, 4096, 256) bf16.
// grid (C/64=4, P/64=64, B=8), block 256. Destination lives in d_out (dead
// until the final projection GEMM overwrites every element).
// ---------------------------------------------------------------------------
__global__ __launch_bounds__(256) void transpose_cp(const void* __restrict__ xv,
                                                    ushortT* __restrict__ xT,
                                                    const int* __restrict__ flagp) {
    __shared__ __align__(16) ushortT tile[64][65];
    const int b  = blockIdx.z;
    const int c0 = blockIdx.x * 64;
    const int p0 = blockIdx.y * 64;
    const int t  = threadIdx.x;
    const int isBf = *flagp;

    if (isBf) {
        const ushortT* xb = (const ushortT*)xv + (size_t)b * 256 * 4096;
#pragma unroll
        for (int it = 0; it < 2; it++) {
            int id  = t + it * 256;          // 0..511
            int row = id >> 3;               // c row 0..63
            int c8  = (id & 7) * 8;          // p chunk
            ushort8v v = *(const ushort8v*)(xb + (size_t)(c0 + row) * 4096 + p0 + c8);
#pragma unroll
            for (int j = 0; j < 8; j++) tile[row][c8 + j] = v[j];
        }
    } else {
        const float* xb = (const float*)xv + (size_t)b * 256 * 4096;
#pragma unroll
        for (int it = 0; it < 4; it++) {
            int id  = t + it * 256;          // 0..1023
            int row = id >> 4;               // c row 0..63
            int c4  = (id & 15) * 4;         // p chunk of 4 floats
            float4 v = *(const float4*)(xb + (size_t)(c0 + row) * 4096 + p0 + c4);
            tile[row][c4 + 0] = f2bf(v.x);
            tile[row][c4 + 1] = f2bf(v.y);
            tile[row][c4 + 2] = f2bf(v.z);
            tile[row][c4 + 3] = f2bf(v.w);
        }
    }
    __syncthreads();
    ushortT* xTb = xT + (size_t)b * 4096 * 256;
#pragma unroll
    for (int it = 0; it < 2; it++) {
        int id   = t + it * 256;             // 0..511
        int prow = id >> 3;                  // p row 0..63
        int cc   = (id & 7) * 8;             // c chunk
        ushort8v v;
#pragma unroll
        for (int j = 0; j < 8; j++) v[j] = tile[cc + j][prow];
        *(ushort8v*)(xTb + (size_t)(p0 + prow) * 256 + c0 + cc) = v;
    }
}

// ---------------------------------------------------------------------------
// GEMM  D[m][n] = sum_k A[m][k] * Bt[n][k]  + bias   (bf16 in, fp32 acc)
// A row-major (lda = K).
// B: bHeadMajor=0 -> row-major (row stride ldb);
//    bHeadMajor=1 -> head-major: Bt[((k>>5)*32768 + n)*32 + (k&31)].
// D: dHeadMajor=1 -> bf16 head-major, written via LDS restage as coalesced
//      16B stores; else row-major (ldd), bf16 or fp32 per (outMode==1 && !*flagp).
// K-loop: software-pipelined, LDS double-buffered, ONE raw s_barrier/iter:
//   waitcnt vmcnt(0)  (own 4 loads from prev iter -> cur buf complete)
//   s_barrier         (all waves' cur-buf loads complete; prev-iter frag
//                      reads are lgkm-drained before their MFMAs issue, so
//                      the buffer being written next is safe)
//   issue next-tile global_load_lds -> other buf   (flies across MFMA section)
//   frag ds_reads + 16 MFMA
// LDS tiles XOR-chunk-swizzled (2-way instead of 4-way bank aliasing).
// 128x128 tile, BK=32, 4 waves each owning a 64x64 quadrant (4x4 MFMA).
// grid: (N/128, M/128, batches); Bt/D batch-strided (sBb/sDb elements).
// ---------------------------------------------------------------------------
__global__ __launch_bounds__(256) void gemm_bt(const ushortT* __restrict__ A,
                                               const ushortT* __restrict__ Bt, long long sBb,
                                               int ldb, int bHeadMajor,
                                               void* __restrict__ D, long long sDb,
                                               int ldd, int dHeadMajor,
                                               const float* __restrict__ bias, int biasAlongM,
                                               int K, int outMode, const int* __restrict__ flagp) {
    __shared__ __align__(16) ushortT pool[16384];   // 32 KB: [A0|B0|A1|B1] / epilogue tile

    const int of32 = (outMode == 1) && (*flagp == 0);
    const int bz = blockIdx.z;
    Bt += (size_t)bz * sBb;

    const int n0   = blockIdx.x * 128;
    const int m0   = blockIdx.y * 128;
    const int t    = threadIdx.x;
    const int wv   = t >> 6;
    const int lane = t & 63;
    const int lm   = lane & 15;
    const int quad = lane >> 4;
    const int wm   = wv & 1;     // wave's 64-row quadrant (m)
    const int wn   = wv >> 1;    // wave's 64-col quadrant (n)

    float4v acc[4][4];
#pragma unroll
    for (int i = 0; i < 4; i++)
#pragma unroll
        for (int j = 0; j < 4; j++) { float4v z = {0.f, 0.f, 0.f, 0.f}; acc[i][j] = z; }

    // staging: 512 16B-chunks per tile-pair, this thread's 2 chunk-pairs
    const int cid0 = wv * 128 + lane;          // j=0 chunk id
    auto stage = [&](int kt, int buf) {
        ushortT* Ab = pool + buf * 8192;
        ushortT* Bb = pool + buf * 8192 + 4096;
#pragma unroll
        for (int j = 0; j < 2; j++) {
            int cid = cid0 + j * 64;
            int row = cid >> 2;
            int c8  = cid & 3;
            int gc  = c8 ^ ((row >> 1) & 3);   // swizzled chunk (same 64B segment)
            const ushortT* ga = A + (size_t)(m0 + row) * K + kt * 32 + gc * 8;
            const ushortT* gb = bHeadMajor
                ? Bt + ((size_t)kt * 32768 + (n0 + row)) * 32 + gc * 8
                : Bt + (size_t)(n0 + row) * ldb + kt * 32 + gc * 8;
            gld_lds16(ga, Ab + (size_t)(wv * 128 + j * 64) * 8);
            gld_lds16(gb, Bb + (size_t)(wv * 128 + j * 64) * 8);
        }
    };

    const int nkt = K >> 5;
    stage(0, 0);
    for (int kt = 0; kt < nkt; ++kt) {
        const int cur = kt & 1;
        asm volatile("s_waitcnt vmcnt(0)" ::: "memory");   // own cur-buf loads done
        asm volatile("s_barrier" ::: "memory");            // everyone's done
        if (kt + 1 < nkt) stage(kt + 1, cur ^ 1);          // prefetch flies over MFMA

        const ushortT* Ab = pool + cur * 8192;
        const ushortT* Bb = pool + cur * 8192 + 4096;
        short8 af[4], bfr[4];
#pragma unroll
        for (int i = 0; i < 4; i++) {
            int r = wm * 64 + i * 16 + lm;
            int slot = quad ^ ((r >> 1) & 3);
            af[i] = *(const short8*)&Ab[r * 32 + slot * 8];
        }
#pragma unroll
        for (int j = 0; j < 4; j++) {
            int r = wn * 64 + j * 16 + lm;
            int slot = quad ^ ((r >> 1) & 3);
            bfr[j] = *(const short8*)&Bb[r * 32 + slot * 8];
        }
#pragma unroll
        for (int i = 0; i < 4; i++)
#pragma unroll
            for (int j = 0; j < 4; j++)
                acc[i][j] = __builtin_amdgcn_mfma_f32_16x16x32_bf16(af[i], bfr[j], acc[i][j], 0, 0, 0);
    }

    // epilogue: C/D layout col = lane&15, row = quad*4 + reg
    if (dHeadMajor) {
        // Stage 128x128 bf16 tile in LDS (chunk-XOR swizzle on (r&7)), then
        // write 4 groups x 8KB fully-contiguous with ushort8 stores.
        __syncthreads();   // full drain before pool reuse
#pragma unroll
        for (int i = 0; i < 4; i++) {
#pragma unroll
            for (int j = 0; j < 4; j++) {
                int c = wn * 64 + j * 16 + lm;
#pragma unroll
                for (int rg = 0; rg < 4; rg++) {
                    int r = wm * 64 + i * 16 + quad * 4 + rg;
                    float v = acc[i][j][rg] + bias[biasAlongM ? (m0 + r) : (n0 + c)];
                    int chunk = (c >> 3) ^ (r & 7);
                    pool[r * 128 + chunk * 8 + (c & 7)] = f2bf(v);
                }
            }
        }
        __syncthreads();
        ushortT* Dh = (ushortT*)D + (size_t)bz * sDb;
#pragma unroll
        for (int g = 0; g < 4; g++) {
            ushortT* base = Dh + ((size_t)((n0 >> 5) + g) * 32768 + m0) * 32;
#pragma unroll
            for (int it = 0; it < 2; it++) {
                int id = it * 256 + t;          // 0..511
                int r  = id >> 2;
                int cb = id & 3;                // 8-chunk within group
                int pch = (g * 4 + cb) ^ (r & 7);
                ushort8v v = *(const ushort8v*)&pool[r * 128 + pch * 8];
                *(ushort8v*)(base + r * 32 + cb * 8) = v;
            }
        }
    } else {
        float*   Df = (float*)D   + (size_t)bz * sDb;
        ushortT* Dh = (ushortT*)D + (size_t)bz * sDb;
#pragma unroll
        for (int i = 0; i < 4; i++) {
            int r0 = m0 + wm * 64 + i * 16 + quad * 4;
#pragma unroll
            for (int j = 0; j < 4; j++) {
                int c = n0 + wn * 64 + j * 16 + lm;
#pragma unroll
                for (int rg = 0; rg < 4; rg++) {
                    int r = r0 + rg;
                    float v = acc[i][j][rg] + bias[biasAlongM ? r : c];
                    if (of32) Df[(size_t)r * ldd + c] = v;
                    else      Dh[(size_t)r * ldd + c] = f2bf(v);
                }
            }
        }
    }
}

// ---------------------------------------------------------------------------
// Multi-dilated 3x3 local attention, IN-PLACE on HEAD-MAJOR bf16 qkv:
// qkv[(part*8+hd)*32768 + bp][32], part in {q,k,v}.
// One wave = 64 consecutive pixels (one image row) of ONE head -> all q/k/v
// loads are contiguous 4KB/wave segments; hh bounds are wave-uniform.
// Thread writes only its own q slice (k/v never written) -> race-free.
// ---------------------------------------------------------------------------
__global__ __launch_bounds__(256) void attn_k(ushortT* qkv) {
    const int gt   = blockIdx.x * 256 + threadIdx.x;
    const int lane = gt & 63;
    const int wid  = gt >> 6;          // 0..4095
    const int hd   = wid >> 9;         // 0..7  (512 waves per head)
    const int rowI = wid & 511;        // b*64 + h
    const int b    = rowI >> 6;
    const int h    = rowI & 63;
    const int w    = lane;
    const int dil  = (hd & 3) + 1;     // DILATIONS = [1,2,3,4]
    const int bp   = b * 4096 + h * 64 + w;

    ushortT*       qp    = qkv + ((size_t)hd * 32768 + bp) * 32;
    const ushortT* kbase = qkv + ((size_t)(8  + hd) * 32768 + (size_t)b * 4096) * 32;
    const ushortT* vbase = qkv + ((size_t)(16 + hd) * 32768 + (size_t)b * 4096) * 32;

    float q[32];
#pragma unroll
    for (int c = 0; c < 4; c++) {
        ushort8v v = *(const ushort8v*)(qp + c * 8);
#pragma unroll
        for (int j = 0; j < 8; j++) q[c * 8 + j] = bf2f(v[j]);
    }

    float lgt[9];
    int   nb[9];
    unsigned vmask = 0;
#pragma unroll
    for (int ii = 0; ii < 3; ii++) {
#pragma unroll
        for (int jj = 0; jj < 3; jj++) {
            int idx = ii * 3 + jj;
            int hh = h + (ii - 1) * dil;   // wave-uniform
            int ww = w + (jj - 1) * dil;
            bool ok = ((unsigned)hh < 64u) && ((unsigned)ww < 64u);
            int pp = (hh << 6) + ww;
            nb[idx] = pp;
            float l = 0.f;                 // OOB: k is zero-padded -> logit exactly 0
            if (ok) {
                vmask |= (1u << idx);
                const ushortT* kp = kbase + (size_t)pp * 32;
#pragma unroll
                for (int c = 0; c < 4; c++) {
                    ushort8v v = *(const ushort8v*)(kp + c * 8);
#pragma unroll
                    for (int j = 0; j < 8; j++) l += q[c * 8 + j] * bf2f(v[j]);
                }
                l *= ATT_SCALE;
            }
            lgt[idx] = l;
        }
    }

    float mx = lgt[0];
#pragma unroll
    for (int i = 1; i < 9; i++) mx = fmaxf(mx, lgt[i]);
    float e[9], s = 0.f;
#pragma unroll
    for (int i = 0; i < 9; i++) { e[i] = __expf(lgt[i] - mx); s += e[i]; }
    const float inv = 1.f / s;

    float acc[32];
#pragma unroll
    for (int d = 0; d < 32; d++) acc[d] = 0.f;
#pragma unroll
    for (int idx = 0; idx < 9; idx++) {
        if ((vmask >> idx) & 1u) {        // OOB: v = 0, contributes nothing (e[idx] stays in s)
            float pj = e[idx] * inv;
            const ushortT* vp = vbase + (size_t)nb[idx] * 32;
#pragma unroll
            for (int c = 0; c < 4; c++) {
                ushort8v v = *(const ushort8v*)(vp + c * 8);
#pragma unroll
                for (int j = 0; j < 8; j++) acc[c * 8 + j] += pj * bf2f(v[j]);
            }
        }
    }

#pragma unroll
    for (int c = 0; c < 4; c++) {         // overwrite own q slice
        ushort8v v;
#pragma unroll
        for (int j = 0; j < 8; j++) v[j] = f2bf(acc[c * 8 + j]);
        *(ushort8v*)(qp + c * 8) = v;
    }
}

// ---------------------------------------------------------------------------
extern "C" void kernel_launch(void* const* d_in, const int* in_sizes, int n_in,
                              void* d_out, int out_size, void* d_ws, size_t ws_size,
                              hipStream_t stream) {
    const void* x      = d_in[0];  // (8,256,64,64)   fp32 or bf16 (probed)
    const void* w_qkv  = d_in[1];  // (768,256)
    const void* b_qkv  = d_in[2];  // (768,)
    const void* w_proj = d_in[3];  // (256,256)
    const void* b_proj = d_in[4];  // (256,)

    // ws layout (256B-aligned): flag | bqF | bpF | wqkvB | wprojB | qkv(head-major)
    char* ws = (char*)d_ws;
    int*     flag   = (int*)ws;                        // 4 B
    float*   bqF    = (float*)(ws + 256);              // 768 f32
    float*   bpF    = (float*)(ws + 3328);             // 256 f32
    ushortT* wqkvB  = (ushortT*)(ws + 4352);           // 196608 bf16
    ushortT* wprojB = (ushortT*)(ws + 397568);         // 65536 bf16
    ushortT* qkv    = (ushortT*)(ws + 528640);         // 24 x 32768 x 32 bf16 = 48 MiB
    ushortT* xT     = (ushortT*)d_out;                 // (32768,256) bf16 scratch in d_out;
                                                       // fully overwritten by the final GEMM

    // 0) probe input dtype
    detect_dtype<<<1, 256, 0, stream>>>((const ushortT*)x, flag);

    // 0b) weights -> bf16, biases -> fp32
    convert_params<<<1028, 256, 0, stream>>>(w_qkv, w_proj, b_qkv, b_proj,
                                             wqkvB, wprojB, bqF, bpF, flag);

    // 1) x (B,C,P) -> xT (B,P,C) bf16
    transpose_cp<<<dim3(4, 64, 8), 256, 0, stream>>>(x, xT, flag);

    // 2) qkv head-major = xT(32768,256) @ w_qkv^T + b_qkv   (bias along n)
    gemm_bt<<<dim3(6, 256, 1), 256, 0, stream>>>(xT, wqkvB, 0, 256, 0,
                                                 qkv, 0, 0, 1,
                                                 bqF, 0, 256, 0, flag);

    // 3) attention in-place on head-major qkv (y overwrites q slices)
    attn_k<<<dim3(1024), 256, 0, stream>>>(qkv);

    // 4) out(b,256,4096) = w_proj @ y(b)^T + b_proj  (bias along m; out dtype per flag)
    //    y = q-slices of head-major qkv; batch stride = 4096*32 elements
    gemm_bt<<<dim3(32, 2, 8), 256, 0, stream>>>(wprojB, qkv, (long long)4096 * 32, 0, 1,
                                                d_out, (long long)256 * 4096, 4096, 0,
                                                bpF, 1, 256, 1, flag);
}